// Round 5
// baseline (522.678 us; speedup 1.0000x reference)
//
#include <hip/hip_runtime.h>

#define B_  8
#define T_  4096
#define C_  1024
#define TP  4098                 // T + 2 halo rows
#define NW  (1024 * 1024)        // weights per k-slice

typedef __bf16 bf16x8 __attribute__((ext_vector_type(8)));
typedef float  f32x4  __attribute__((ext_vector_type(4)));

__device__ __forceinline__ unsigned short f2bf_rne(float f) {
    unsigned u = __float_as_uint(f);
    u += 0x7FFFu + ((u >> 16) & 1u);
    return (unsigned short)(u >> 16);
}

// async global->LDS, 16B per lane; LDS dest = wave-uniform base + lane*16
#define GLOAD16(g, l)                                                        \
    __builtin_amdgcn_global_load_lds(                                        \
        (const __attribute__((address_space(1))) void*)(g),                  \
        (__attribute__((address_space(3))) void*)(l), 16, 0, 0)

// ================================================================ K1: fused
// blocks [0,2048): LN stats + absmax partials (16 rows/block)
// blocks [2048,2112): xq halo zero-init
// blocks [2112,2304): |W| sum partials (16384 els/block)
__global__ __launch_bounds__(256) void prefix1_kernel(
    const float* __restrict__ x, const float* __restrict__ lng,
    const float* __restrict__ lnb, const float* __restrict__ W,
    float2* __restrict__ stats, float* __restrict__ gpart,
    float* __restrict__ wpart, unsigned short* __restrict__ xq) {
    const int blk = blockIdx.x;
    const int tid = threadIdx.x;

    if (blk >= 2112) {                        // ---- |W| partials (192 blocks)
        const int wb = blk - 2112;
        size_t i0 = ((size_t)wb * 256 + tid) * 16;   // dense 16 f32/thread? 192*256*16=786k... need 64
        // 192 blocks x 256 thr x 64 els = 3145728
        i0 = ((size_t)wb * 256 + tid) * 64;
        float s = 0.0f;
#pragma unroll
        for (int j = 0; j < 16; ++j) {
            float4 a = *(const float4*)(W + i0 + j * 4);
            s += fabsf(a.x) + fabsf(a.y) + fabsf(a.z) + fabsf(a.w);
        }
#pragma unroll
        for (int off = 32; off > 0; off >>= 1) s += __shfl_down(s, off, 64);
        __shared__ float ps[4];
        const int wave = tid >> 6, lane = tid & 63;
        if (lane == 0) ps[wave] = s;
        __syncthreads();
        if (tid == 0) wpart[wb] = (ps[0] + ps[1]) + (ps[2] + ps[3]);
        return;
    }
    if (blk >= 2048) {                        // ---- xq halo init (64 blocks)
        const int i = (blk - 2048) * 256 + tid;      // 16384 ids
        const int r16 = i >> 10;                     // 0..15 pad rows
        const int b = r16 >> 1, side = r16 & 1;
        xq[((size_t)b * TP + (size_t)side * (TP - 1)) * C_ + (i & 1023)] = 0;
        return;
    }

    // ---- stats + absmax (2048 blocks, 16 rows each; wave w: 4 rows)
    const int w = tid >> 6, l = tid & 63;
    const int row0 = blk * 16;                // b*T + t; 4096%16==0: no b-straddle
    __shared__ unsigned lmax[1024];
#pragma unroll
    for (int k = 0; k < 4; ++k) lmax[tid + k * 256] = 0u;
    __syncthreads();

    const int c0 = l * 16;
    float gv[16], bv[16], m[16];
#pragma unroll
    for (int j = 0; j < 4; ++j) {
        *(float4*)&gv[j * 4] = *(const float4*)(lng + c0 + j * 4);
        *(float4*)&bv[j * 4] = *(const float4*)(lnb + c0 + j * 4);
    }
#pragma unroll
    for (int j = 0; j < 16; ++j) m[j] = 0.0f;

#pragma unroll 2
    for (int rr = 0; rr < 4; ++rr) {
        const int row = row0 + w * 4 + rr;
        const float* xr = x + (size_t)row * C_ + c0;
        float v[16];
#pragma unroll
        for (int j = 0; j < 4; ++j) *(float4*)&v[j * 4] = *(const float4*)(xr + j * 4);
        float s = 0.0f, s2 = 0.0f;
#pragma unroll
        for (int j = 0; j < 16; ++j) { s += v[j]; s2 += v[j] * v[j]; }
#pragma unroll
        for (int off = 1; off < 64; off <<= 1) {
            s  += __shfl_xor(s,  off, 64);
            s2 += __shfl_xor(s2, off, 64);
        }
        const float mu   = s * (1.0f / C_);
        const float var  = fmaxf(s2 * (1.0f / C_) - mu * mu, 0.0f);
        const float rstd = 1.0f / sqrtf(var + 1e-5f);
        if (l == 0) stats[row] = make_float2(mu, rstd);
#pragma unroll
        for (int j = 0; j < 16; ++j)
            m[j] = fmaxf(m[j], fabsf((v[j] - mu) * rstd * gv[j] + bv[j]));
    }
    // m >= 0 so uint compare == float compare
#pragma unroll
    for (int j = 0; j < 16; ++j) atomicMax(&lmax[c0 + j], __float_as_uint(m[j]));
    __syncthreads();
#pragma unroll
    for (int k = 0; k < 4; ++k) {
        const int c = tid + k * 256;
        gpart[(size_t)blk * 1024 + c] = __uint_as_float(lmax[c]);
    }
}

// ================================================================ K2: fused reduce
// blocks [0,32): gamma_x[b][c] = max over 256 partial rows (b = blk>>2)
// block 32: wsum = sum(wpart[0..191]) in fp64
__global__ __launch_bounds__(256) void prefix2_kernel(
    const float* __restrict__ gpart, const float* __restrict__ wpart,
    float* __restrict__ gamma_x, double* __restrict__ wsum) {
    const int blk = blockIdx.x;
    const int tid = threadIdx.x;
    if (blk < 32) {
        const int c = (blk & 3) * 256 + tid;
        const int b = blk >> 2;
        const float* p = gpart + (size_t)b * 256 * 1024 + c;
        float m = 0.0f;
#pragma unroll 8
        for (int i = 0; i < 256; ++i) m = fmaxf(m, p[(size_t)i * 1024]);
        gamma_x[b * 1024 + c] = m;
        return;
    }
    double s = (tid < 192) ? (double)wpart[tid] : 0.0;
#pragma unroll
    for (int off = 32; off > 0; off >>= 1) s += __shfl_down(s, off, 64);
    __shared__ double ps[4];
    const int wave = tid >> 6, lane = tid & 63;
    if (lane == 0) ps[wave] = s;
    __syncthreads();
    if (tid == 0) *wsum = (ps[0] + ps[1]) + (ps[2] + ps[3]);
}

// ================================================================ K3: fused quant
// blocks [0,8192): activation quant (4 rows/block) -> padded xq
// blocks [8192,12288): weight quant + repack wq[k][o][i]
__device__ __forceinline__ unsigned short quant1s(float xv, float2 s, float g,
                                                  float be, float sc) {
    float xn = (xv - s.x) * s.y * g + be;
    float r  = rintf(xn * sc);                        // ref: round then clip
    r = fminf(fmaxf(r, -127.0f), 127.0f);
    return f2bf_rne(r);                               // integer |r|<=127: exact
}

__global__ __launch_bounds__(256) void quant_kernel(
    const float* __restrict__ x, const float2* __restrict__ stats,
    const float* __restrict__ lng, const float* __restrict__ lnb,
    const float* __restrict__ gamma_x, unsigned short* __restrict__ xq,
    const float* __restrict__ W, const double* __restrict__ wsum,
    unsigned short* __restrict__ wq, float* __restrict__ beta_out) {
    const int blk = blockIdx.x;
    const int tid = threadIdx.x;

    if (blk >= 8192) {                        // ---- weight quant (4096 blocks)
        const int gid = (blk - 8192) * 256 + tid;     // (o,i) pair
        const float beta = fmaxf((float)(*wsum * (1.0 / 3145728.0)), 1e-5f);
        if (gid == 0) *beta_out = beta;
        const float* wp = W + (size_t)gid * 3;
#pragma unroll
        for (int k = 0; k < 3; ++k) {
            float s  = wp[k] / beta;                  // ref: clip then round
            float r  = rintf(fminf(fmaxf(s, -1.0f), 1.0f));
            wq[(size_t)k * NW + gid] = f2bf_rne(r);   // {-1,0,1} exact in bf16
        }
        return;
    }

    // ---- activation quant (8192 blocks, 4 rows each)
    const int r0 = blk * 4;                   // 4 rows share b
    const int b = r0 >> 12;
    const int c = tid * 4;
    float4 gv = *(const float4*)(lng + c);
    float4 bv = *(const float4*)(lnb + c);
    float4 gm = *(const float4*)(gamma_x + b * C_ + c);
    float4 sc;
    sc.x = 127.0f / fmaxf(gm.x, 1e-5f);
    sc.y = 127.0f / fmaxf(gm.y, 1e-5f);
    sc.z = 127.0f / fmaxf(gm.z, 1e-5f);
    sc.w = 127.0f / fmaxf(gm.w, 1e-5f);
#pragma unroll
    for (int rr = 0; rr < 4; ++rr) {
        const int row = r0 + rr, t = row & 4095;
        const float2 s = stats[row];
        float4 xv = *(const float4*)(x + (size_t)row * C_ + c);
        ushort4 qv;
        qv.x = quant1s(xv.x, s, gv.x, bv.x, sc.x);
        qv.y = quant1s(xv.y, s, gv.y, bv.y, sc.y);
        qv.z = quant1s(xv.z, s, gv.z, bv.z, sc.z);
        qv.w = quant1s(xv.w, s, gv.w, bv.w, sc.w);
        *(ushort4*)(xq + ((size_t)b * TP + t + 1) * C_ + c) = qv;
    }
}

// ---------------------------------------------------------------- conv-as-GEMM: 256x256 tile, 8-wave,
// 4-phase/K-tile, SINGLE barrier per phase (round-3 schedule, 235us proven).
// All LDS fragment reads issued one phase EARLY: af-reload interleaved after each
// 4-MFMA group, bf-reload post-MFMA on k-transition phases. Counted vmcnt:
// VM6 at P0/P2 steady, VM6/VM4/VM0 tail. Swizzled K-half-major LDS (0 conflicts).
__global__ __launch_bounds__(512, 2) void gemm_kernel(
    const unsigned short* __restrict__ xq,   // [B][TP][C] bf16 (padded)
    const unsigned short* __restrict__ wq,   // [3][O][I] bf16 ternary
    const float* __restrict__ gamma_x,       // [B][C]
    const float* __restrict__ beta_p,        // scalar
    float* __restrict__ out) {               // [B][T][O] fp32
    __shared__ __align__(16) unsigned short sA[2][2][8192];  // 64 KiB
    __shared__ __align__(16) unsigned short sB[2][2][8192];  // 64 KiB

    const int tid = threadIdx.x;
    const int w   = tid >> 6;                 // wave 0..7 (2M x 4N)
    const int l   = tid & 63;
    const int q   = l >> 4;                   // k-granule 0..3
    const int lr  = l & 15;                   // fragment row
    const int g8    = (q ^ ((lr >> 1) & 3)) * 8;           // read granule (swizzled)
    const int srcg8 = ((l & 3) ^ ((l >> 3) & 3)) * 8;      // stage src granule (same involution)

    // XCD-bijective decode: 512 blocks = 8 xcd-slots x 64; 4 n-tiles of one
    // (b,mt) A-panel share an XCD-slot (L2 reuse of A).
    const int d  = blockIdx.x;
    const int gg = (d & 7) + ((d >> 5) << 3);   // (b,mt) group 0..127
    const int nt = (d >> 3) & 3;
    const int b  = gg >> 4;
    const int t0 = (gg & 15) << 8;
    const int n0 = nt << 8;

    const int wm = (w >> 2) * 128;            // wave M offset (2 x 128)
    const int wn = (w & 3) * 64;              // wave N offset (4 x 64)

    const unsigned short* A0 = xq + (size_t)(b * TP + t0) * C_;
    const unsigned short* Bq = wq + (size_t)n0 * C_;

    f32x4 acc[8][4] = {};
    bf16x8 af[4], bf[4];

#define RD_A(MI, ABU, AKH, AMS)                                                   \
    af[MI] = *(const bf16x8*)&sA[ABU][AKH][(wm + (AMS) * 64 + (MI) * 16 + lr) * 32 + g8]
#define RD_B_ALL(BBU, BKH) do {                                                   \
        _Pragma("unroll")                                                         \
        for (int ni = 0; ni < 4; ++ni)                                            \
            bf[ni] = *(const bf16x8*)&sB[BBU][BKH][(wn + ni * 16 + lr) * 32 + g8];\
    } while (0)

#define STG(DST, GP) do {                                                         \
        GLOAD16((GP) + (size_t)(w * 16 + (l >> 2)) * C_ + srcg8, (DST) + w * 512);\
        GLOAD16((GP) + (size_t)(w * 16 + (l >> 2) + 128) * C_ + srcg8,            \
                (DST) + 4096 + w * 512);                                          \
    } while (0)
#define STG_A(S, KH) STG(&sA[(S) & 1][KH][0], A0 + (S) * 64 + (KH) * 32)
#define STG_B(S, KH) STG(&sB[(S) & 1][KH][0],                                     \
        Bq + (size_t)((S) >> 4) * NW + ((S) & 15) * 64 + (KH) * 32)

#define VM8 asm volatile("s_waitcnt vmcnt(8)" ::: "memory")
#define VM6 asm volatile("s_waitcnt vmcnt(6)" ::: "memory")
#define VM4 asm volatile("s_waitcnt vmcnt(4)" ::: "memory")
#define VM0 asm volatile("s_waitcnt vmcnt(0)" ::: "memory")
#define VMX do {} while (0)

// phase: [stage issue][wait prev reads][MFMA x16 with af-reload interleaved]
//        [bf-reload][vm][barrier]
#define PH(AM, DOAF, ABU, AMS, AKH, DOBF, BBU, BKH, STGC, VMC, BAR) do {          \
        STGC;                                                                     \
        asm volatile("s_waitcnt lgkmcnt(0)" ::: "memory");                        \
        __builtin_amdgcn_sched_barrier(0);                                        \
        __builtin_amdgcn_s_setprio(1);                                            \
        _Pragma("unroll")                                                         \
        for (int mi = 0; mi < 4; ++mi) {                                          \
            _Pragma("unroll")                                                     \
            for (int ni = 0; ni < 4; ++ni)                                        \
                acc[(AM) * 4 + mi][ni] = __builtin_amdgcn_mfma_f32_16x16x32_bf16( \
                    af[mi], bf[ni], acc[(AM) * 4 + mi][ni], 0, 0, 0);             \
            if (DOAF) { RD_A(mi, ABU, AKH, AMS); }                                \
            __builtin_amdgcn_sched_barrier(0);                                    \
        }                                                                         \
        __builtin_amdgcn_s_setprio(0);                                            \
        if (DOBF) { RD_B_ALL(BBU, BKH); }                                         \
        VMC;                                                                      \
        if (BAR) { __builtin_amdgcn_s_barrier();                                  \
                   __builtin_amdgcn_sched_barrier(0); }                           \
    } while (0)

// P0: mfma m0/k0, af->m1 k0, VM6 (retires (kt,k1) staged slab)
// P1: mfma m1/k0, af->m0 k1, bf->k1
// P2: mfma m0/k1, af->m1 k1, VM6 (retires (kt+1,k0) staged slab)
// P3: mfma m1/k1, af->next-buf m0 k0, bf->next-buf k0
#define TILE(BU, S0C, S1C, S2C, S3C, VA, VB, AF3, BF3, BAR3) do {                 \
        PH(0, 1, BU, 1, 0, 0, 0, 0, S0C, VA, 1);                                  \
        PH(1, 1, BU, 0, 1, 1, BU, 1, S1C, VMX, 1);                                \
        PH(0, 1, BU, 1, 1, 0, 0, 0, S2C, VB, 1);                                  \
        PH(1, AF3, (BU) ^ 1, 0, 0, BF3, (BU) ^ 1, 0, S3C, VMX, BAR3);             \
    } while (0)

#define TILE_ST(KT, BU)                                                           \
    TILE(BU, { STG_A((KT) + 1, 1); }, { STG_B((KT) + 1, 1); },                    \
             { STG_A((KT) + 2, 0); }, { STG_B((KT) + 2, 0); }, VM6, VM6, 1, 1, 1)

    // prologue: tile0 (k0,k1) + tile1.k0 = 12 loads; VM8 -> tile0.k0 landed
    STG_A(0, 0); STG_B(0, 0);
    STG_A(0, 1); STG_B(0, 1);
    STG_A(1, 0); STG_B(1, 0);
    VM8;
    __builtin_amdgcn_s_barrier();
    __builtin_amdgcn_sched_barrier(0);
    RD_A(0, 0, 0, 0); RD_A(1, 0, 0, 0); RD_A(2, 0, 0, 0); RD_A(3, 0, 0, 0);
    RD_B_ALL(0, 0);

#pragma unroll 1
    for (int kt = 0; kt < 46; kt += 2) {
        TILE_ST(kt, 0);
        TILE_ST(kt + 1, 1);
    }
    // tail: tile 46 stages only (47,k1); tile 47 stages nothing
    TILE(0, { STG_A(47, 1); }, { STG_B(47, 1); }, {}, {}, VM6, VM4, 1, 1, 1);
    TILE(1, {}, {}, {}, {}, VM0, VMX, 0, 0, 0);

    // epilogue: y = acc * beta * gamma_x[b,o] / 127  (C/D: col=lane&15, row=quad*4+reg)
    const float beta = *beta_p;
#pragma unroll
    for (int ni = 0; ni < 4; ++ni) {
        const int o = n0 + wn + ni * 16 + lr;
        const float sc = beta * fmaxf(gamma_x[b * C_ + o], 1e-5f) * (1.0f / 127.0f);
#pragma unroll
        for (int mi = 0; mi < 8; ++mi) {
#pragma unroll
            for (int r = 0; r < 4; ++r) {
                const int t = t0 + wm + mi * 16 + q * 4 + r;
                out[(size_t)(b * T_ + t) * C_ + o] = acc[mi][ni][r] * sc;
            }
        }
    }
#undef RD_A
#undef RD_B_ALL
#undef STG
#undef STG_A
#undef STG_B
#undef PH
#undef TILE
#undef TILE_ST
}

// ---------------------------------------------------------------- launch
extern "C" void kernel_launch(void* const* d_in, const int* in_sizes, int n_in,
                              void* d_out, int out_size, void* d_ws, size_t ws_size,
                              hipStream_t stream) {
    const float* x   = (const float*)d_in[0];  // [8,4096,1024] fp32
    const float* lng = (const float*)d_in[1];  // [1024] fp32
    const float* lnb = (const float*)d_in[2];  // [1024] fp32
    const float* W   = (const float*)d_in[3];  // [1024,1024,3] fp32
    float* out = (float*)d_out;                // fp32 output [8,4096,1024]

    char* ws = (char*)d_ws;
    float2*         stats  = (float2*)(ws + 0);          //   262144 B
    float*          gamma  = (float*) (ws + 262144);     //    32768 B
    double*         wsum   = (double*)(ws + 294912);     //        8 B
    float*          beta   = (float*) (ws + 294920);     //        4 B (+pad)
    unsigned short* wq     = (unsigned short*)(ws + 294928);   // 6291456 B
    unsigned short* xq     = (unsigned short*)(ws + 6586384);  // 67141632 B -> 73.7 MB total
    float*          gpart  = out;                    // [2048][1024] f32 = 8 MB scratch
    float*          wpart  = out + 4 * 1024 * 1024;  // 192 floats @ +16 MB (clear of gpart)

    prefix1_kernel<<<2304,  256, 0, stream>>>(x, lng, lnb, W, stats, gpart, wpart, xq);
    prefix2_kernel<<<33,    256, 0, stream>>>(gpart, wpart, gamma, wsum);
    quant_kernel  <<<12288, 256, 0, stream>>>(x, stats, lng, lnb, gamma, xq,
                                              W, wsum, wq, beta);
    gemm_kernel   <<<dim3(512), 512, 0, stream>>>(xq, wq, gamma, beta, out);
}

// Round 7
// 424.060 us; speedup vs baseline: 1.2326x; 1.2326x over previous
//
#include <hip/hip_runtime.h>

#define B_  8
#define T_  4096
#define C_  1024
#define TP  4098                 // T + 2 halo rows
#define NW  (1024 * 1024)        // weight bytes per k-slice (O*I i8)

typedef int   i32x4 __attribute__((ext_vector_type(4)));
typedef float f32x4 __attribute__((ext_vector_type(4)));

// async global->LDS, 16B per lane; LDS dest = wave-uniform base + lane*16
#define GLOAD16(g, l)                                                        \
    __builtin_amdgcn_global_load_lds(                                        \
        (const __attribute__((address_space(1))) void*)(g),                  \
        (__attribute__((address_space(3))) void*)(l), 16, 0, 0)

// ================================================================ K1: fused
// blocks [0,2048): LN stats + absmax partials (16 rows/block)
// blocks [2048,2064): xq halo zero-init (16 KB as int stores)
// blocks [2064,2256): |W| sum partials (64 els/thread)
__global__ __launch_bounds__(256) void prefix1_kernel(
    const float* __restrict__ x, const float* __restrict__ lng,
    const float* __restrict__ lnb, const float* __restrict__ W,
    float2* __restrict__ stats, float* __restrict__ gpart,
    float* __restrict__ wpart, signed char* __restrict__ xq8) {
    const int blk = blockIdx.x;
    const int tid = threadIdx.x;

    if (blk >= 2064) {                        // ---- |W| partials (192 blocks)
        const int wb = blk - 2064;
        size_t i0 = ((size_t)wb * 256 + tid) * 64;   // 192*256*64 = 3145728
        float s = 0.0f;
#pragma unroll
        for (int j = 0; j < 16; ++j) {
            float4 a = *(const float4*)(W + i0 + j * 4);
            s += fabsf(a.x) + fabsf(a.y) + fabsf(a.z) + fabsf(a.w);
        }
#pragma unroll
        for (int off = 32; off > 0; off >>= 1) s += __shfl_down(s, off, 64);
        __shared__ float ps[4];
        const int wave = tid >> 6, lane = tid & 63;
        if (lane == 0) ps[wave] = s;
        __syncthreads();
        if (tid == 0) wpart[wb] = (ps[0] + ps[1]) + (ps[2] + ps[3]);
        return;
    }
    if (blk >= 2048) {                        // ---- xq8 halo init (16 blocks)
        const int i = (blk - 2048) * 256 + tid;      // 4096 ids x 4B = 16KB
        const int r16 = i >> 8;                      // 0..15 pad rows
        const int b = r16 >> 1, side = r16 & 1;
        *(int*)(xq8 + ((size_t)b * TP + (size_t)side * (TP - 1)) * C_
                + (i & 255) * 4) = 0;
        return;
    }

    // ---- stats + absmax (2048 blocks, 16 rows each; wave w: 4 rows)
    const int w = tid >> 6, l = tid & 63;
    const int row0 = blk * 16;                // b*T + t; 4096%16==0: no b-straddle
    __shared__ unsigned lmax[1024];
#pragma unroll
    for (int k = 0; k < 4; ++k) lmax[tid + k * 256] = 0u;
    __syncthreads();

    const int c0 = l * 16;
    float gv[16], bv[16], m[16];
#pragma unroll
    for (int j = 0; j < 4; ++j) {
        *(float4*)&gv[j * 4] = *(const float4*)(lng + c0 + j * 4);
        *(float4*)&bv[j * 4] = *(const float4*)(lnb + c0 + j * 4);
    }
#pragma unroll
    for (int j = 0; j < 16; ++j) m[j] = 0.0f;

#pragma unroll 2
    for (int rr = 0; rr < 4; ++rr) {
        const int row = row0 + w * 4 + rr;
        const float* xr = x + (size_t)row * C_ + c0;
        float v[16];
#pragma unroll
        for (int j = 0; j < 4; ++j) *(float4*)&v[j * 4] = *(const float4*)(xr + j * 4);
        float s = 0.0f, s2 = 0.0f;
#pragma unroll
        for (int j = 0; j < 16; ++j) { s += v[j]; s2 += v[j] * v[j]; }
#pragma unroll
        for (int off = 1; off < 64; off <<= 1) {
            s  += __shfl_xor(s,  off, 64);
            s2 += __shfl_xor(s2, off, 64);
        }
        const float mu   = s * (1.0f / C_);
        const float var  = fmaxf(s2 * (1.0f / C_) - mu * mu, 0.0f);
        const float rstd = 1.0f / sqrtf(var + 1e-5f);
        if (l == 0) stats[row] = make_float2(mu, rstd);
#pragma unroll
        for (int j = 0; j < 16; ++j)
            m[j] = fmaxf(m[j], fabsf((v[j] - mu) * rstd * gv[j] + bv[j]));
    }
    // m >= 0 so uint compare == float compare
#pragma unroll
    for (int j = 0; j < 16; ++j) atomicMax(&lmax[c0 + j], __float_as_uint(m[j]));
    __syncthreads();
#pragma unroll
    for (int k = 0; k < 4; ++k) {
        const int c = tid + k * 256;
        gpart[(size_t)blk * 1024 + c] = __uint_as_float(lmax[c]);
    }
}

// ================================================================ K2: fused reduce
__global__ __launch_bounds__(256) void prefix2_kernel(
    const float* __restrict__ gpart, const float* __restrict__ wpart,
    float* __restrict__ gamma_x, double* __restrict__ wsum) {
    const int blk = blockIdx.x;
    const int tid = threadIdx.x;
    if (blk < 32) {
        const int c = (blk & 3) * 256 + tid;
        const int b = blk >> 2;
        const float* p = gpart + (size_t)b * 256 * 1024 + c;
        float m = 0.0f;
#pragma unroll 8
        for (int i = 0; i < 256; ++i) m = fmaxf(m, p[(size_t)i * 1024]);
        gamma_x[b * 1024 + c] = m;
        return;
    }
    double s = (tid < 192) ? (double)wpart[tid] : 0.0;
#pragma unroll
    for (int off = 32; off > 0; off >>= 1) s += __shfl_down(s, off, 64);
    __shared__ double ps[4];
    const int wave = tid >> 6, lane = tid & 63;
    if (lane == 0) ps[wave] = s;
    __syncthreads();
    if (tid == 0) *wsum = (ps[0] + ps[1]) + (ps[2] + ps[3]);
}

// ================================================================ K3: fused quant (i8 outputs)
__device__ __forceinline__ signed char quant1s(float xv, float2 s, float g,
                                               float be, float sc) {
    float xn = (xv - s.x) * s.y * g + be;
    float r  = rintf(xn * sc);                        // ref: round then clip
    r = fminf(fmaxf(r, -127.0f), 127.0f);
    return (signed char)(int)r;
}

__global__ __launch_bounds__(256) void quant_kernel(
    const float* __restrict__ x, const float2* __restrict__ stats,
    const float* __restrict__ lng, const float* __restrict__ lnb,
    const float* __restrict__ gamma_x, signed char* __restrict__ xq8,
    const float* __restrict__ W, const double* __restrict__ wsum,
    signed char* __restrict__ wq8, float* __restrict__ beta_out) {
    const int blk = blockIdx.x;
    const int tid = threadIdx.x;

    if (blk >= 8192) {                        // ---- weight quant (4096 blocks)
        const int gid = (blk - 8192) * 256 + tid;     // (o,i) pair
        const float beta = fmaxf((float)(*wsum * (1.0 / 3145728.0)), 1e-5f);
        if (gid == 0) *beta_out = beta;
        const float* wp = W + (size_t)gid * 3;
#pragma unroll
        for (int k = 0; k < 3; ++k) {
            float s  = wp[k] / beta;                  // ref: clip then round
            float r  = rintf(fminf(fmaxf(s, -1.0f), 1.0f));
            wq8[(size_t)k * NW + gid] = (signed char)(int)r;
        }
        return;
    }

    // ---- activation quant (8192 blocks, 4 rows each)
    const int r0 = blk * 4;                   // 4 rows share b
    const int b = r0 >> 12;
    const int c = tid * 4;
    float4 gv = *(const float4*)(lng + c);
    float4 bv = *(const float4*)(lnb + c);
    float4 gm = *(const float4*)(gamma_x + b * C_ + c);
    float4 sc;
    sc.x = 127.0f / fmaxf(gm.x, 1e-5f);
    sc.y = 127.0f / fmaxf(gm.y, 1e-5f);
    sc.z = 127.0f / fmaxf(gm.z, 1e-5f);
    sc.w = 127.0f / fmaxf(gm.w, 1e-5f);
#pragma unroll
    for (int rr = 0; rr < 4; ++rr) {
        const int row = r0 + rr, t = row & 4095;
        const float2 s = stats[row];
        float4 xv = *(const float4*)(x + (size_t)row * C_ + c);
        char4 qv;
        qv.x = quant1s(xv.x, s, gv.x, bv.x, sc.x);
        qv.y = quant1s(xv.y, s, gv.y, bv.y, sc.y);
        qv.z = quant1s(xv.z, s, gv.z, bv.z, sc.z);
        qv.w = quant1s(xv.w, s, gv.w, bv.w, sc.w);
        *(char4*)(xq8 + ((size_t)b * TP + t + 1) * C_ + c) = qv;
    }
}

// ---------------------------------------------------------------- conv-as-GEMM, int8 MFMA (exact).
// 256x256 tile, 8-wave; mfma_i32_16x16x64_i8: one MFMA eats a full BK=64 k-tile
// -> 32 MFMA/wave/tile = 2 phases x 16. i8 halves LDS bytes, staging loads, and
// HBM fetch vs bf16. LDS [4 slots][256 rows][64 B] linear (8 accesses/bank =
// conflict-free minimum, no swizzle; gload_lds dest stays linear). Schedule =
// r3-proven: reads one phase early inside MFMA cluster, 1 barrier/phase,
// counted vmcnt (prologue 12 loads -> VM4; steady VM4 at P1; VM0 at tile 45).
__global__ __launch_bounds__(512, 2) void gemm_kernel(
    const signed char* __restrict__ xq8,     // [B][TP][C] i8 (padded)
    const signed char* __restrict__ wq8,     // [3][O][I] i8 ternary
    const float* __restrict__ gamma_x,       // [B][C]
    const float* __restrict__ beta_p,        // scalar
    float* __restrict__ out) {               // [B][T][O] fp32
    __shared__ __align__(16) signed char sA8[4][16384];  // 64 KiB
    __shared__ __align__(16) signed char sB8[4][16384];  // 64 KiB

    const int tid = threadIdx.x;
    const int w   = tid >> 6;                 // wave 0..7 (2M x 4N)
    const int l   = tid & 63;
    const int q   = l >> 4;                   // k-granule 0..3 (16 B each)
    const int lr  = l & 15;                   // fragment row

    // XCD-bijective decode: 512 blocks = 8 xcd-slots x 64; 4 n-tiles of one
    // (b,mt) A-panel share an XCD-slot (L2 reuse of A).
    const int d  = blockIdx.x;
    const int gg = (d & 7) + ((d >> 5) << 3);   // (b,mt) group 0..127
    const int nt = (d >> 3) & 3;
    const int b  = gg >> 4;
    const int t0 = (gg & 15) << 8;
    const int n0 = nt << 8;

    const int wm = (w >> 2) * 128;            // wave M offset (2 x 128)
    const int wn = (w & 3) * 64;              // wave N offset (4 x 64)

    const signed char* A0 = xq8 + (size_t)(b * TP + t0) * C_;   // row = 1024 B
    const signed char* Bq = wq8 + (size_t)n0 * C_;

    i32x4 acc[8][4] = {};
    i32x4 af[4], bf[4];

#define RD_A8(MI, SL, MS)                                                         \
    af[MI] = *(const i32x4*)&sA8[SL][(wm + (MS) * 64 + (MI) * 16 + lr) * 64 + q * 16]
#define RD_B8(SL) do {                                                            \
        _Pragma("unroll")                                                         \
        for (int ni = 0; ni < 4; ++ni)                                            \
            bf[ni] = *(const i32x4*)&sB8[SL][(wn + ni * 16 + lr) * 64 + q * 16];  \
    } while (0)

    // stage one 16 KB tile slab (2 gloads/wave): rows w*16+(l>>2) and +128
#define STG_A8(SLOT, S) do {                                                      \
        signed char* dA = &sA8[SLOT][0];                                          \
        const signed char* gA = A0 + (size_t)(S) * 64;                            \
        GLOAD16(gA + (size_t)(w * 16 + (l >> 2)) * C_ + (l & 3) * 16,             \
                dA + w * 1024);                                                   \
        GLOAD16(gA + (size_t)(w * 16 + (l >> 2) + 128) * C_ + (l & 3) * 16,       \
                dA + 8192 + w * 1024);                                            \
    } while (0)
#define STG_B8(SLOT, S) do {                                                      \
        signed char* dB = &sB8[SLOT][0];                                          \
        const signed char* gB = Bq + (size_t)((S) >> 4) * NW + ((S) & 15) * 64;   \
        GLOAD16(gB + (size_t)(w * 16 + (l >> 2)) * C_ + (l & 3) * 16,             \
                dB + w * 1024);                                                   \
        GLOAD16(gB + (size_t)(w * 16 + (l >> 2) + 128) * C_ + (l & 3) * 16,       \
                dB + 8192 + w * 1024);                                            \
    } while (0)

#define VM4 asm volatile("s_waitcnt vmcnt(4)" ::: "memory")
#define VM0 asm volatile("s_waitcnt vmcnt(0)" ::: "memory")
#define VMX do {} while (0)

// phase: [stage issue][wait prev-phase reads][16 MFMA w/ af-reload interleaved]
//        [bf-reload][vm][barrier]
#define PH8(AM, DOAF, ASL, AMS, DOBF, BSL, STGC, VMC, BAR) do {                   \
        STGC;                                                                     \
        asm volatile("s_waitcnt lgkmcnt(0)" ::: "memory");                        \
        __builtin_amdgcn_sched_barrier(0);                                        \
        __builtin_amdgcn_s_setprio(1);                                            \
        _Pragma("unroll")                                                         \
        for (int mi = 0; mi < 4; ++mi) {                                          \
            _Pragma("unroll")                                                     \
            for (int ni = 0; ni < 4; ++ni)                                        \
                acc[(AM) * 4 + mi][ni] = __builtin_amdgcn_mfma_i32_16x16x64_i8(   \
                    af[mi], bf[ni], acc[(AM) * 4 + mi][ni], 0, 0, 0);             \
            if (DOAF) { RD_A8(mi, ASL, AMS); }                                    \
            __builtin_amdgcn_sched_barrier(0);                                    \
        }                                                                         \
        __builtin_amdgcn_s_setprio(0);                                            \
        if (DOBF) { RD_B8(BSL); }                                                 \
        VMC;                                                                      \
        if (BAR) { __builtin_amdgcn_s_barrier();                                  \
                   __builtin_amdgcn_sched_barrier(0); }                           \
    } while (0)

// tile kt (slab C0 = kt&3): P0: mfma m0-3, af->(kt,m4-7), stage A(kt+3)
//                           P1: mfma m4-7, af->(kt+1,m0-3), bf->(kt+1), stage B(kt+3), VM
#define TILE8(C0, S, STG_ON, VM1C, AF1, BF1, BAR1) do {                           \
        PH8(0, 1, (C0), 1, 0, 0,                                                  \
            { if (STG_ON) { STG_A8(((C0) + 3) & 3, (S) + 3); } }, VMX, 1);        \
        PH8(1, AF1, ((C0) + 1) & 3, 0, BF1, ((C0) + 1) & 3,                       \
            { if (STG_ON) { STG_B8(((C0) + 3) & 3, (S) + 3); } }, VM1C, BAR1);    \
    } while (0)

    // prologue: stage tiles 0,1,2 (12 loads); VM4 -> tiles 0,1 landed; preload
    STG_A8(0, 0); STG_B8(0, 0);
    STG_A8(1, 1); STG_B8(1, 1);
    STG_A8(2, 2); STG_B8(2, 2);
    VM4;
    __builtin_amdgcn_s_barrier();
    __builtin_amdgcn_sched_barrier(0);
    RD_A8(0, 0, 0); RD_A8(1, 0, 0); RD_A8(2, 0, 0); RD_A8(3, 0, 0);
    RD_B8(0);

#pragma unroll 1
    for (int it = 0; it < 11; ++it) {         // tiles 0..43
        const int s0 = it * 4;
        TILE8(0, s0 + 0, 1, VM4, 1, 1, 1);
        TILE8(1, s0 + 1, 1, VM4, 1, 1, 1);
        TILE8(2, s0 + 2, 1, VM4, 1, 1, 1);
        TILE8(3, s0 + 3, 1, VM4, 1, 1, 1);
    }
    TILE8(0, 44, 1, VM4, 1, 1, 1);            // stages tile 47
    TILE8(1, 45, 0, VM0, 1, 1, 1);            // drain: tile 47 landed
    TILE8(2, 46, 0, VMX, 1, 1, 1);
    TILE8(3, 47, 0, VMX, 0, 0, 0);            // last: no next reads

    // epilogue: y = (float)acc * beta * gamma_x[b,o] / 127  (C/D: col=lane&15, row=q*4+r)
    const float beta = *beta_p;
#pragma unroll
    for (int ni = 0; ni < 4; ++ni) {
        const int o = n0 + wn + ni * 16 + lr;
        const float sc = beta * fmaxf(gamma_x[b * C_ + o], 1e-5f) * (1.0f / 127.0f);
#pragma unroll
        for (int mi = 0; mi < 8; ++mi) {
#pragma unroll
            for (int r = 0; r < 4; ++r) {
                const int t = t0 + wm + mi * 16 + q * 4 + r;
                out[(size_t)(b * T_ + t) * C_ + o] = (float)acc[mi][ni][r] * sc;
            }
        }
    }
#undef RD_A8
#undef RD_B8
#undef STG_A8
#undef STG_B8
#undef PH8
#undef TILE8
}

// ---------------------------------------------------------------- launch
extern "C" void kernel_launch(void* const* d_in, const int* in_sizes, int n_in,
                              void* d_out, int out_size, void* d_ws, size_t ws_size,
                              hipStream_t stream) {
    const float* x   = (const float*)d_in[0];  // [8,4096,1024] fp32
    const float* lng = (const float*)d_in[1];  // [1024] fp32
    const float* lnb = (const float*)d_in[2];  // [1024] fp32
    const float* W   = (const float*)d_in[3];  // [1024,1024,3] fp32
    float* out = (float*)d_out;                // fp32 output [8,4096,1024]

    char* ws = (char*)d_ws;
    float2*      stats = (float2*)(ws + 0);          //   262144 B
    float*       gamma = (float*) (ws + 262144);     //    32768 B
    double*      wsum  = (double*)(ws + 294912);     //        8 B
    float*       beta  = (float*) (ws + 294920);     //        4 B (+pad)
    signed char* wq8   = (signed char*)(ws + 294928);    // 3145728 B
    signed char* xq8   = (signed char*)(ws + 3440656);   // 33570816 B -> ~37 MB total
    float*       gpart = out;                    // [2048][1024] f32 = 8 MB scratch
    float*       wpart = out + 4 * 1024 * 1024;  // 192 floats @ +16 MB (clear of gpart)

    prefix1_kernel<<<2256,  256, 0, stream>>>(x, lng, lnb, W, stats, gpart, wpart, xq8);
    prefix2_kernel<<<33,    256, 0, stream>>>(gpart, wpart, gamma, wsum);
    quant_kernel  <<<12288, 256, 0, stream>>>(x, stats, lng, lnb, gamma, xq8,
                                              W, wsum, wq8, beta);
    gemm_kernel   <<<dim3(512), 512, 0, stream>>>(xq8, wq8, gamma, beta, out);
}

// Round 10
// 422.343 us; speedup vs baseline: 1.2376x; 1.0041x over previous
//
#include <hip/hip_runtime.h>

#define B_  8
#define T_  4096
#define C_  1024
#define TP  4098                 // T + 2 halo rows
#define NW  (1024 * 1024)        // weight bytes per k-slice (O*I i8)

typedef int   i32x4 __attribute__((ext_vector_type(4)));
typedef float f32x4 __attribute__((ext_vector_type(4)));

// async global->LDS, 16B per lane; LDS dest = wave-uniform base + lane*16
#define GLOAD16(g, l)                                                        \
    __builtin_amdgcn_global_load_lds(                                        \
        (const __attribute__((address_space(1))) void*)(g),                  \
        (__attribute__((address_space(3))) void*)(l), 16, 0, 0)

// ================================================================ K1: fused
// blocks [0,2048): LN stats + absmax partials (16 rows/block)
// blocks [2048,2064): xq halo zero-init (16 KB as int stores)
// blocks [2064,2256): |W| sum partials (64 els/thread)
__global__ __launch_bounds__(256) void prefix1_kernel(
    const float* __restrict__ x, const float* __restrict__ lng,
    const float* __restrict__ lnb, const float* __restrict__ W,
    float2* __restrict__ stats, float* __restrict__ gpart,
    float* __restrict__ wpart, signed char* __restrict__ xq8) {
    const int blk = blockIdx.x;
    const int tid = threadIdx.x;

    if (blk >= 2064) {                        // ---- |W| partials (192 blocks)
        const int wb = blk - 2064;
        size_t i0 = ((size_t)wb * 256 + tid) * 64;   // 192*256*64 = 3145728
        float s = 0.0f;
#pragma unroll
        for (int j = 0; j < 16; ++j) {
            float4 a = *(const float4*)(W + i0 + j * 4);
            s += fabsf(a.x) + fabsf(a.y) + fabsf(a.z) + fabsf(a.w);
        }
#pragma unroll
        for (int off = 32; off > 0; off >>= 1) s += __shfl_down(s, off, 64);
        __shared__ float ps[4];
        const int wave = tid >> 6, lane = tid & 63;
        if (lane == 0) ps[wave] = s;
        __syncthreads();
        if (tid == 0) wpart[wb] = (ps[0] + ps[1]) + (ps[2] + ps[3]);
        return;
    }
    if (blk >= 2048) {                        // ---- xq8 halo init (16 blocks)
        const int i = (blk - 2048) * 256 + tid;      // 4096 ids x 4B = 16KB
        const int r16 = i >> 8;                      // 0..15 pad rows
        const int b = r16 >> 1, side = r16 & 1;
        *(int*)(xq8 + ((size_t)b * TP + (size_t)side * (TP - 1)) * C_
                + (i & 255) * 4) = 0;
        return;
    }

    // ---- stats + absmax (2048 blocks, 16 rows each; wave w: 4 rows)
    const int w = tid >> 6, l = tid & 63;
    const int row0 = blk * 16;                // b*T + t; 4096%16==0: no b-straddle
    __shared__ unsigned lmax[1024];
#pragma unroll
    for (int k = 0; k < 4; ++k) lmax[tid + k * 256] = 0u;
    __syncthreads();

    const int c0 = l * 16;
    float gv[16], bv[16], m[16];
#pragma unroll
    for (int j = 0; j < 4; ++j) {
        *(float4*)&gv[j * 4] = *(const float4*)(lng + c0 + j * 4);
        *(float4*)&bv[j * 4] = *(const float4*)(lnb + c0 + j * 4);
    }
#pragma unroll
    for (int j = 0; j < 16; ++j) m[j] = 0.0f;

#pragma unroll 2
    for (int rr = 0; rr < 4; ++rr) {
        const int row = row0 + w * 4 + rr;
        const float* xr = x + (size_t)row * C_ + c0;
        float v[16];
#pragma unroll
        for (int j = 0; j < 4; ++j) *(float4*)&v[j * 4] = *(const float4*)(xr + j * 4);
        float s = 0.0f, s2 = 0.0f;
#pragma unroll
        for (int j = 0; j < 16; ++j) { s += v[j]; s2 += v[j] * v[j]; }
#pragma unroll
        for (int off = 1; off < 64; off <<= 1) {
            s  += __shfl_xor(s,  off, 64);
            s2 += __shfl_xor(s2, off, 64);
        }
        const float mu   = s * (1.0f / C_);
        const float var  = fmaxf(s2 * (1.0f / C_) - mu * mu, 0.0f);
        const float rstd = 1.0f / sqrtf(var + 1e-5f);
        if (l == 0) stats[row] = make_float2(mu, rstd);
#pragma unroll
        for (int j = 0; j < 16; ++j)
            m[j] = fmaxf(m[j], fabsf((v[j] - mu) * rstd * gv[j] + bv[j]));
    }
    // m >= 0 so uint compare == float compare
#pragma unroll
    for (int j = 0; j < 16; ++j) atomicMax(&lmax[c0 + j], __float_as_uint(m[j]));
    __syncthreads();
#pragma unroll
    for (int k = 0; k < 4; ++k) {
        const int c = tid + k * 256;
        gpart[(size_t)blk * 1024 + c] = __uint_as_float(lmax[c]);
    }
}

// ================================================================ K2: fused reduce
__global__ __launch_bounds__(256) void prefix2_kernel(
    const float* __restrict__ gpart, const float* __restrict__ wpart,
    float* __restrict__ gamma_x, double* __restrict__ wsum) {
    const int blk = blockIdx.x;
    const int tid = threadIdx.x;
    if (blk < 32) {
        const int c = (blk & 3) * 256 + tid;
        const int b = blk >> 2;
        const float* p = gpart + (size_t)b * 256 * 1024 + c;
        float m = 0.0f;
#pragma unroll 8
        for (int i = 0; i < 256; ++i) m = fmaxf(m, p[(size_t)i * 1024]);
        gamma_x[b * 1024 + c] = m;
        return;
    }
    double s = (tid < 192) ? (double)wpart[tid] : 0.0;
#pragma unroll
    for (int off = 32; off > 0; off >>= 1) s += __shfl_down(s, off, 64);
    __shared__ double ps[4];
    const int wave = tid >> 6, lane = tid & 63;
    if (lane == 0) ps[wave] = s;
    __syncthreads();
    if (tid == 0) *wsum = (ps[0] + ps[1]) + (ps[2] + ps[3]);
}

// ================================================================ K3: fused quant (i8 outputs)
__device__ __forceinline__ signed char quant1s(float xv, float2 s, float g,
                                               float be, float sc) {
    float xn = (xv - s.x) * s.y * g + be;
    float r  = rintf(xn * sc);                        // ref: round then clip
    r = fminf(fmaxf(r, -127.0f), 127.0f);
    return (signed char)(int)r;
}

__global__ __launch_bounds__(256) void quant_kernel(
    const float* __restrict__ x, const float2* __restrict__ stats,
    const float* __restrict__ lng, const float* __restrict__ lnb,
    const float* __restrict__ gamma_x, signed char* __restrict__ xq8,
    const float* __restrict__ W, const double* __restrict__ wsum,
    signed char* __restrict__ wq8, float* __restrict__ beta_out) {
    const int blk = blockIdx.x;
    const int tid = threadIdx.x;

    if (blk >= 8192) {                        // ---- weight quant (4096 blocks)
        const int gid = (blk - 8192) * 256 + tid;     // (o,i) pair
        const float beta = fmaxf((float)(*wsum * (1.0 / 3145728.0)), 1e-5f);
        if (gid == 0) *beta_out = beta;
        const float* wp = W + (size_t)gid * 3;
#pragma unroll
        for (int k = 0; k < 3; ++k) {
            float s  = wp[k] / beta;                  // ref: clip then round
            float r  = rintf(fminf(fmaxf(s, -1.0f), 1.0f));
            wq8[(size_t)k * NW + gid] = (signed char)(int)r;
        }
        return;
    }

    // ---- activation quant (8192 blocks, 4 rows each)
    const int r0 = blk * 4;                   // 4 rows share b
    const int b = r0 >> 12;
    const int c = tid * 4;
    float4 gv = *(const float4*)(lng + c);
    float4 bv = *(const float4*)(lnb + c);
    float4 gm = *(const float4*)(gamma_x + b * C_ + c);
    float4 sc;
    sc.x = 127.0f / fmaxf(gm.x, 1e-5f);
    sc.y = 127.0f / fmaxf(gm.y, 1e-5f);
    sc.z = 127.0f / fmaxf(gm.z, 1e-5f);
    sc.w = 127.0f / fmaxf(gm.w, 1e-5f);
#pragma unroll
    for (int rr = 0; rr < 4; ++rr) {
        const int row = r0 + rr, t = row & 4095;
        const float2 s = stats[row];
        float4 xv = *(const float4*)(x + (size_t)row * C_ + c);
        char4 qv;
        qv.x = quant1s(xv.x, s, gv.x, bv.x, sc.x);
        qv.y = quant1s(xv.y, s, gv.y, bv.y, sc.y);
        qv.z = quant1s(xv.z, s, gv.z, bv.z, sc.z);
        qv.w = quant1s(xv.w, s, gv.w, bv.w, sc.w);
        *(char4*)(xq8 + ((size_t)b * TP + t + 1) * C_ + c) = qv;
    }
}

// ---------------------------------------------------------------- conv-as-GEMM, int8 MFMA (exact).
// 256x256 tile, 8-wave; mfma_i32_16x16x64_i8: one MFMA eats a full BK=64 k-tile.
// LDS [4 slots][256 rows][4 granules x 16B] with XOR granule swizzle
// g ^= (row>>1)&3 -- byte-identical to the r2-r5 bf16 layout that measured
// ZERO bank conflicts (linear layout measured 9.4e6: 8 lanes/q-group share a
// bank with distinct addresses = 8-way). Swizzle applied BOTH sides (rule 21):
// pre-swizzled per-lane GLOBAL source (LDS dest linear for gload_lds) + swizzled
// ds_read granule. Schedule = r3-proven: reads one phase early inside MFMA
// cluster, 1 barrier/phase, counted vmcnt (VM4 steady, VM0 drain at tile 45).
__global__ __launch_bounds__(512, 2) void gemm_kernel(
    const signed char* __restrict__ xq8,     // [B][TP][C] i8 (padded)
    const signed char* __restrict__ wq8,     // [3][O][I] i8 ternary
    const float* __restrict__ gamma_x,       // [B][C]
    const float* __restrict__ beta_p,        // scalar
    float* __restrict__ out) {               // [B][T][O] fp32
    __shared__ __align__(16) signed char sA8[4][16384];  // 64 KiB
    __shared__ __align__(16) signed char sB8[4][16384];  // 64 KiB

    const int tid = threadIdx.x;
    const int w   = tid >> 6;                 // wave 0..7 (2M x 4N)
    const int l   = tid & 63;
    const int q   = l >> 4;                   // k-granule 0..3 (16 B each)
    const int lr  = l & 15;                   // fragment row
    const int g16  = (q ^ ((lr >> 1) & 3)) * 16;          // read granule (swizzled)
    const int sg16 = ((l & 3) ^ ((l >> 3) & 3)) * 16;     // stage src granule (same involution)

    // XCD-bijective decode: 512 blocks = 8 xcd-slots x 64; 4 n-tiles of one
    // (b,mt) A-panel share an XCD-slot (L2 reuse of A).
    const int d  = blockIdx.x;
    const int gg = (d & 7) + ((d >> 5) << 3);   // (b,mt) group 0..127
    const int nt = (d >> 3) & 3;
    const int b  = gg >> 4;
    const int t0 = (gg & 15) << 8;
    const int n0 = nt << 8;

    const int wm = (w >> 2) * 128;            // wave M offset (2 x 128)
    const int wn = (w & 3) * 64;              // wave N offset (4 x 64)

    const signed char* A0 = xq8 + (size_t)(b * TP + t0) * C_;   // row = 1024 B
    const signed char* Bq = wq8 + (size_t)n0 * C_;

    i32x4 acc[8][4] = {};
    i32x4 af[4], bf[4];

// read granule: (row>>1)&3 == (lr>>1)&3 since wm/ms*64/mi*16/wn/ni*16 all
// contribute 0 mod 4 after >>1  -> g16 precomputed per-thread.
#define RD_A8(MI, SL, MS)                                                         \
    af[MI] = *(const i32x4*)&sA8[SL][(wm + (MS) * 64 + (MI) * 16 + lr) * 64 + g16]
#define RD_B8(SL) do {                                                            \
        _Pragma("unroll")                                                         \
        for (int ni = 0; ni < 4; ++ni)                                            \
            bf[ni] = *(const i32x4*)&sB8[SL][(wn + ni * 16 + lr) * 64 + g16];     \
    } while (0)

    // stage one 16 KB tile slab (2 gloads/wave): rows w*16+(l>>2) and +128.
    // LDS dest linear (lane*16); source granule pre-swizzled: slot (row, l&3)
    // receives global granule (l&3)^((row>>1)&3), (row>>1)&3 == (l>>3)&3.
#define STG_A8(SLOT, S) do {                                                      \
        signed char* dA = &sA8[SLOT][0];                                          \
        const signed char* gA = A0 + (size_t)(S) * 64;                            \
        GLOAD16(gA + (size_t)(w * 16 + (l >> 2)) * C_ + sg16,                     \
                dA + w * 1024);                                                   \
        GLOAD16(gA + (size_t)(w * 16 + (l >> 2) + 128) * C_ + sg16,               \
                dA + 8192 + w * 1024);                                            \
    } while (0)
#define STG_B8(SLOT, S) do {                                                      \
        signed char* dB = &sB8[SLOT][0];                                          \
        const signed char* gB = Bq + (size_t)((S) >> 4) * NW + ((S) & 15) * 64;   \
        GLOAD16(gB + (size_t)(w * 16 + (l >> 2)) * C_ + sg16,                     \
                dB + w * 1024);                                                   \
        GLOAD16(gB + (size_t)(w * 16 + (l >> 2) + 128) * C_ + sg16,               \
                dB + 8192 + w * 1024);                                            \
    } while (0)

#define VM4 asm volatile("s_waitcnt vmcnt(4)" ::: "memory")
#define VM0 asm volatile("s_waitcnt vmcnt(0)" ::: "memory")
#define VMX do {} while (0)

// phase: [stage issue][wait prev-phase reads][16 MFMA w/ af-reload interleaved]
//        [bf-reload][vm][barrier]
#define PH8(AM, DOAF, ASL, AMS, DOBF, BSL, STGC, VMC, BAR) do {                   \
        STGC;                                                                     \
        asm volatile("s_waitcnt lgkmcnt(0)" ::: "memory");                        \
        __builtin_amdgcn_sched_barrier(0);                                        \
        __builtin_amdgcn_s_setprio(1);                                            \
        _Pragma("unroll")                                                         \
        for (int mi = 0; mi < 4; ++mi) {                                          \
            _Pragma("unroll")                                                     \
            for (int ni = 0; ni < 4; ++ni)                                        \
                acc[(AM) * 4 + mi][ni] = __builtin_amdgcn_mfma_i32_16x16x64_i8(   \
                    af[mi], bf[ni], acc[(AM) * 4 + mi][ni], 0, 0, 0);             \
            if (DOAF) { RD_A8(mi, ASL, AMS); }                                    \
            __builtin_amdgcn_sched_barrier(0);                                    \
        }                                                                         \
        __builtin_amdgcn_s_setprio(0);                                            \
        if (DOBF) { RD_B8(BSL); }                                                 \
        VMC;                                                                      \
        if (BAR) { __builtin_amdgcn_s_barrier();                                  \
                   __builtin_amdgcn_sched_barrier(0); }                           \
    } while (0)

// tile kt (slab C0 = kt&3): P0: mfma m0-3, af->(kt,m4-7), stage A(kt+3)
//                           P1: mfma m4-7, af->(kt+1,m0-3), bf->(kt+1), stage B(kt+3), VM
#define TILE8(C0, S, STG_ON, VM1C, AF1, BF1, BAR1) do {                           \
        PH8(0, 1, (C0), 1, 0, 0,                                                  \
            { if (STG_ON) { STG_A8(((C0) + 3) & 3, (S) + 3); } }, VMX, 1);        \
        PH8(1, AF1, ((C0) + 1) & 3, 0, BF1, ((C0) + 1) & 3,                       \
            { if (STG_ON) { STG_B8(((C0) + 3) & 3, (S) + 3); } }, VM1C, BAR1);    \
    } while (0)

    // prologue: stage tiles 0,1,2 (12 loads); VM4 -> tiles 0,1 landed; preload
    STG_A8(0, 0); STG_B8(0, 0);
    STG_A8(1, 1); STG_B8(1, 1);
    STG_A8(2, 2); STG_B8(2, 2);
    VM4;
    __builtin_amdgcn_s_barrier();
    __builtin_amdgcn_sched_barrier(0);
    RD_A8(0, 0, 0); RD_A8(1, 0, 0); RD_A8(2, 0, 0); RD_A8(3, 0, 0);
    RD_B8(0);

#pragma unroll 1
    for (int it = 0; it < 11; ++it) {         // tiles 0..43
        const int s0 = it * 4;
        TILE8(0, s0 + 0, 1, VM4, 1, 1, 1);
        TILE8(1, s0 + 1, 1, VM4, 1, 1, 1);
        TILE8(2, s0 + 2, 1, VM4, 1, 1, 1);
        TILE8(3, s0 + 3, 1, VM4, 1, 1, 1);
    }
    TILE8(0, 44, 1, VM4, 1, 1, 1);            // stages tile 47
    TILE8(1, 45, 0, VM0, 1, 1, 1);            // drain: tile 47 landed
    TILE8(2, 46, 0, VMX, 1, 1, 1);
    TILE8(3, 47, 0, VMX, 0, 0, 0);            // last: no next reads

    // epilogue: y = (float)acc * beta * gamma_x[b,o] / 127  (C/D: col=lane&15, row=q*4+r)
    const float beta = *beta_p;
#pragma unroll
    for (int ni = 0; ni < 4; ++ni) {
        const int o = n0 + wn + ni * 16 + lr;
        const float sc = beta * fmaxf(gamma_x[b * C_ + o], 1e-5f) * (1.0f / 127.0f);
#pragma unroll
        for (int mi = 0; mi < 8; ++mi) {
#pragma unroll
            for (int r = 0; r < 4; ++r) {
                const int t = t0 + wm + mi * 16 + q * 4 + r;
                out[(size_t)(b * T_ + t) * C_ + o] = (float)acc[mi][ni][r] * sc;
            }
        }
    }
#undef RD_A8
#undef RD_B8
#undef STG_A8
#undef STG_B8
#undef PH8
#undef TILE8
}

// ---------------------------------------------------------------- launch
extern "C" void kernel_launch(void* const* d_in, const int* in_sizes, int n_in,
                              void* d_out, int out_size, void* d_ws, size_t ws_size,
                              hipStream_t stream) {
    const float* x   = (const float*)d_in[0];  // [8,4096,1024] fp32
    const float* lng = (const float*)d_in[1];  // [1024] fp32
    const float* lnb = (const float*)d_in[2];  // [1024] fp32
    const float* W   = (const float*)d_in[3];  // [1024,1024,3] fp32
    float* out = (float*)d_out;                // fp32 output [8,4096,1024]

    char* ws = (char*)d_ws;
    float2*      stats = (float2*)(ws + 0);          //   262144 B
    float*       gamma = (float*) (ws + 262144);     //    32768 B
    double*      wsum  = (double*)(ws + 294912);     //        8 B
    float*       beta  = (float*) (ws + 294920);     //        4 B (+pad)
    signed char* wq8   = (signed char*)(ws + 294928);    // 3145728 B
    signed char* xq8   = (signed char*)(ws + 3440656);   // 33570816 B -> ~37 MB total
    float*       gpart = out;                    // [2048][1024] f32 = 8 MB scratch
    float*       wpart = out + 4 * 1024 * 1024;  // 192 floats @ +16 MB (clear of gpart)

    prefix1_kernel<<<2256,  256, 0, stream>>>(x, lng, lnb, W, stats, gpart, wpart, xq8);
    prefix2_kernel<<<33,    256, 0, stream>>>(gpart, wpart, gamma, wsum);
    quant_kernel  <<<12288, 256, 0, stream>>>(x, stats, lng, lnb, gamma, xq8,
                                              W, wsum, wq8, beta);
    gemm_kernel   <<<dim3(512), 512, 0, stream>>>(xq8, wq8, gamma, beta, out);
}

// Round 11
// 410.405 us; speedup vs baseline: 1.2736x; 1.0291x over previous
//
#include <hip/hip_runtime.h>

#define B_  8
#define T_  4096
#define C_  1024
#define TP  4098                 // T + 2 halo rows
#define NW  (1024 * 1024)        // weight bytes per k-slice (O*I i8)

typedef int   i32x4 __attribute__((ext_vector_type(4)));
typedef float f32x4 __attribute__((ext_vector_type(4)));

// async global->LDS, 16B per lane; LDS dest = wave-uniform base + lane*16
#define GLOAD16(g, l)                                                        \
    __builtin_amdgcn_global_load_lds(                                        \
        (const __attribute__((address_space(1))) void*)(g),                  \
        (__attribute__((address_space(3))) void*)(l), 16, 0, 0)

// ================================================================ K1: fused
// blocks [0,2048): LN stats + absmax partials (16 rows/block)
// blocks [2048,2064): xq halo zero-init (16 KB as int stores)
// blocks [2064,2256): |W| sum partials (64 els/thread)
__global__ __launch_bounds__(256) void prefix1_kernel(
    const float* __restrict__ x, const float* __restrict__ lng,
    const float* __restrict__ lnb, const float* __restrict__ W,
    float2* __restrict__ stats, float* __restrict__ gpart,
    float* __restrict__ wpart, signed char* __restrict__ xq8) {
    const int blk = blockIdx.x;
    const int tid = threadIdx.x;

    if (blk >= 2064) {                        // ---- |W| partials (192 blocks)
        const int wb = blk - 2064;
        size_t i0 = ((size_t)wb * 256 + tid) * 64;   // 192*256*64 = 3145728
        float s = 0.0f;
#pragma unroll
        for (int j = 0; j < 16; ++j) {
            float4 a = *(const float4*)(W + i0 + j * 4);
            s += fabsf(a.x) + fabsf(a.y) + fabsf(a.z) + fabsf(a.w);
        }
#pragma unroll
        for (int off = 32; off > 0; off >>= 1) s += __shfl_down(s, off, 64);
        __shared__ float ps[4];
        const int wave = tid >> 6, lane = tid & 63;
        if (lane == 0) ps[wave] = s;
        __syncthreads();
        if (tid == 0) wpart[wb] = (ps[0] + ps[1]) + (ps[2] + ps[3]);
        return;
    }
    if (blk >= 2048) {                        // ---- xq8 halo init (16 blocks)
        const int i = (blk - 2048) * 256 + tid;      // 4096 ids x 4B = 16KB
        const int r16 = i >> 8;                      // 0..15 pad rows
        const int b = r16 >> 1, side = r16 & 1;
        *(int*)(xq8 + ((size_t)b * TP + (size_t)side * (TP - 1)) * C_
                + (i & 255) * 4) = 0;
        return;
    }

    // ---- stats + absmax (2048 blocks, 16 rows each; wave w: 4 rows)
    const int w = tid >> 6, l = tid & 63;
    const int row0 = blk * 16;                // b*T + t; 4096%16==0: no b-straddle
    __shared__ unsigned lmax[1024];
#pragma unroll
    for (int k = 0; k < 4; ++k) lmax[tid + k * 256] = 0u;
    __syncthreads();

    const int c0 = l * 16;
    float gv[16], bv[16], m[16];
#pragma unroll
    for (int j = 0; j < 4; ++j) {
        *(float4*)&gv[j * 4] = *(const float4*)(lng + c0 + j * 4);
        *(float4*)&bv[j * 4] = *(const float4*)(lnb + c0 + j * 4);
    }
#pragma unroll
    for (int j = 0; j < 16; ++j) m[j] = 0.0f;

#pragma unroll 2
    for (int rr = 0; rr < 4; ++rr) {
        const int row = row0 + w * 4 + rr;
        const float* xr = x + (size_t)row * C_ + c0;
        float v[16];
#pragma unroll
        for (int j = 0; j < 4; ++j) *(float4*)&v[j * 4] = *(const float4*)(xr + j * 4);
        float s = 0.0f, s2 = 0.0f;
#pragma unroll
        for (int j = 0; j < 16; ++j) { s += v[j]; s2 += v[j] * v[j]; }
#pragma unroll
        for (int off = 1; off < 64; off <<= 1) {
            s  += __shfl_xor(s,  off, 64);
            s2 += __shfl_xor(s2, off, 64);
        }
        const float mu   = s * (1.0f / C_);
        const float var  = fmaxf(s2 * (1.0f / C_) - mu * mu, 0.0f);
        const float rstd = 1.0f / sqrtf(var + 1e-5f);
        if (l == 0) stats[row] = make_float2(mu, rstd);
#pragma unroll
        for (int j = 0; j < 16; ++j)
            m[j] = fmaxf(m[j], fabsf((v[j] - mu) * rstd * gv[j] + bv[j]));
    }
    // m >= 0 so uint compare == float compare
#pragma unroll
    for (int j = 0; j < 16; ++j) atomicMax(&lmax[c0 + j], __float_as_uint(m[j]));
    __syncthreads();
#pragma unroll
    for (int k = 0; k < 4; ++k) {
        const int c = tid + k * 256;
        gpart[(size_t)blk * 1024 + c] = __uint_as_float(lmax[c]);
    }
}

// ================================================================ K2: fused reduce
__global__ __launch_bounds__(256) void prefix2_kernel(
    const float* __restrict__ gpart, const float* __restrict__ wpart,
    float* __restrict__ gamma_x, double* __restrict__ wsum) {
    const int blk = blockIdx.x;
    const int tid = threadIdx.x;
    if (blk < 32) {
        const int c = (blk & 3) * 256 + tid;
        const int b = blk >> 2;
        const float* p = gpart + (size_t)b * 256 * 1024 + c;
        float m = 0.0f;
#pragma unroll 8
        for (int i = 0; i < 256; ++i) m = fmaxf(m, p[(size_t)i * 1024]);
        gamma_x[b * 1024 + c] = m;
        return;
    }
    double s = (tid < 192) ? (double)wpart[tid] : 0.0;
#pragma unroll
    for (int off = 32; off > 0; off >>= 1) s += __shfl_down(s, off, 64);
    __shared__ double ps[4];
    const int wave = tid >> 6, lane = tid & 63;
    if (lane == 0) ps[wave] = s;
    __syncthreads();
    if (tid == 0) *wsum = (ps[0] + ps[1]) + (ps[2] + ps[3]);
}

// ================================================================ K3: fused quant (i8 outputs)
__device__ __forceinline__ signed char quant1s(float xv, float2 s, float g,
                                               float be, float sc) {
    float xn = (xv - s.x) * s.y * g + be;
    float r  = rintf(xn * sc);                        // ref: round then clip
    r = fminf(fmaxf(r, -127.0f), 127.0f);
    return (signed char)(int)r;
}

__global__ __launch_bounds__(256) void quant_kernel(
    const float* __restrict__ x, const float2* __restrict__ stats,
    const float* __restrict__ lng, const float* __restrict__ lnb,
    const float* __restrict__ gamma_x, signed char* __restrict__ xq8,
    const float* __restrict__ W, const double* __restrict__ wsum,
    signed char* __restrict__ wq8, float* __restrict__ beta_out) {
    const int blk = blockIdx.x;
    const int tid = threadIdx.x;

    if (blk >= 8192) {                        // ---- weight quant (4096 blocks)
        const int gid = (blk - 8192) * 256 + tid;     // (o,i) pair
        const float beta = fmaxf((float)(*wsum * (1.0 / 3145728.0)), 1e-5f);
        if (gid == 0) *beta_out = beta;
        const float* wp = W + (size_t)gid * 3;
#pragma unroll
        for (int k = 0; k < 3; ++k) {
            float s  = wp[k] / beta;                  // ref: clip then round
            float r  = rintf(fminf(fmaxf(s, -1.0f), 1.0f));
            wq8[(size_t)k * NW + gid] = (signed char)(int)r;
        }
        return;
    }

    // ---- activation quant (8192 blocks, 4 rows each)
    const int r0 = blk * 4;                   // 4 rows share b
    const int b = r0 >> 12;
    const int c = tid * 4;
    float4 gv = *(const float4*)(lng + c);
    float4 bv = *(const float4*)(lnb + c);
    float4 gm = *(const float4*)(gamma_x + b * C_ + c);
    float4 sc;
    sc.x = 127.0f / fmaxf(gm.x, 1e-5f);
    sc.y = 127.0f / fmaxf(gm.y, 1e-5f);
    sc.z = 127.0f / fmaxf(gm.z, 1e-5f);
    sc.w = 127.0f / fmaxf(gm.w, 1e-5f);
#pragma unroll
    for (int rr = 0; rr < 4; ++rr) {
        const int row = r0 + rr, t = row & 4095;
        const float2 s = stats[row];
        float4 xv = *(const float4*)(x + (size_t)row * C_ + c);
        char4 qv;
        qv.x = quant1s(xv.x, s, gv.x, bv.x, sc.x);
        qv.y = quant1s(xv.y, s, gv.y, bv.y, sc.y);
        qv.z = quant1s(xv.z, s, gv.z, bv.z, sc.z);
        qv.w = quant1s(xv.w, s, gv.w, bv.w, sc.w);
        *(char4*)(xq8 + ((size_t)b * TP + t + 1) * C_ + c) = qv;
    }
}

// ---------------------------------------------------------------- conv-as-GEMM, int8 MFMA (exact).
// 256x256 tile, SIXTEEN waves (4M x 4N, 64x64 each) -> 4 waves/SIMD so TLP hides
// lgkm/vmcnt/barrier stalls (r10 post-mortem: 2 waves/SIMD left both pipes at
// ~40% with no co-scheduling partner). Wave tile 64x64 minimizes per-wave
// fragment traffic (8 KB/tile vs 12), acc drops to 64 VGPR -> fits 128-reg
// budget for 4 waves/SIMD. ONE barrier per K-tile (48 total): 16 MFMA/cluster
// with next-tile af/bf reloads interleaved after last use. Staging: exactly one
// GLOAD16 per wave per slab; depth-3, counted VM2 steady / VM0 tail. LDS layout
// + XOR granule swizzle proven 0-conflict in r10.
__global__ __launch_bounds__(1024, 4) void gemm_kernel(
    const signed char* __restrict__ xq8,     // [B][TP][C] i8 (padded)
    const signed char* __restrict__ wq8,     // [3][O][I] i8 ternary
    const float* __restrict__ gamma_x,       // [B][C]
    const float* __restrict__ beta_p,        // scalar
    float* __restrict__ out) {               // [B][T][O] fp32
    __shared__ __align__(16) signed char sA8[4][16384];  // 64 KiB
    __shared__ __align__(16) signed char sB8[4][16384];  // 64 KiB

    const int tid = threadIdx.x;
    const int w   = tid >> 6;                 // wave 0..15 (4M x 4N)
    const int l   = tid & 63;
    const int q   = l >> 4;                   // k-granule 0..3 (16 B each)
    const int lr  = l & 15;                   // fragment row
    const int g16  = (q ^ ((lr >> 1) & 3)) * 16;          // read granule (swizzled)
    const int sg16 = ((l & 3) ^ ((l >> 3) & 3)) * 16;     // stage src granule (same involution)

    // XCD-bijective decode: 512 blocks = 8 xcd-slots x 64; 4 n-tiles of one
    // (b,mt) A-panel share an XCD-slot (L2 reuse of A).
    const int d  = blockIdx.x;
    const int gg = (d & 7) + ((d >> 5) << 3);   // (b,mt) group 0..127
    const int nt = (d >> 3) & 3;
    const int b  = gg >> 4;
    const int t0 = (gg & 15) << 8;
    const int n0 = nt << 8;

    const int wm = (w >> 2) * 64;             // wave M offset (4 x 64)
    const int wn = (w & 3) * 64;              // wave N offset (4 x 64)

    const signed char* A0 = xq8 + (size_t)(b * TP + t0) * C_;   // row = 1024 B
    const signed char* Bq = wq8 + (size_t)n0 * C_;

    i32x4 acc[4][4] = {};
    i32x4 af[4], bf[4];

// read granule: (row>>1)&3 == (lr>>1)&3 since wm/wn/frag*16 are == 0 mod 16.
#define RD_A8(MI, SL)                                                             \
    af[MI] = *(const i32x4*)&sA8[SL][(wm + (MI) * 16 + lr) * 64 + g16]
#define RD_B8(NI, SL)                                                             \
    bf[NI] = *(const i32x4*)&sB8[SL][(wn + (NI) * 16 + lr) * 64 + g16]

    // stage one 16 KB tile slab: ONE GLOAD16 per wave (16 waves x 1 KB).
    // LDS dest linear (base + lane*16); source granule pre-swizzled:
    // row w*16+(l>>2); (row>>1)&3 == (l>>3)&3.
#define STG_A8(SLOT, S)                                                           \
    GLOAD16(A0 + (size_t)(S) * 64 + (size_t)(w * 16 + (l >> 2)) * C_ + sg16,      \
            &sA8[SLOT][0] + w * 1024)
#define STG_B8(SLOT, S)                                                           \
    GLOAD16(Bq + (size_t)((S) >> 4) * NW + ((S) & 15) * 64                        \
            + (size_t)(w * 16 + (l >> 2)) * C_ + sg16,                            \
            &sB8[SLOT][0] + w * 1024)

#define VM2 asm volatile("s_waitcnt vmcnt(2)" ::: "memory")
#define VM0 asm volatile("s_waitcnt vmcnt(0)" ::: "memory")
#define VMX do {} while (0)
#define SB  __builtin_amdgcn_sched_barrier(0)

#define MFMA8(MI, NI)                                                             \
    acc[MI][NI] = __builtin_amdgcn_mfma_i32_16x16x64_i8(                          \
        af[MI], bf[NI], acc[MI][NI], 0, 0, 0)

#define GRP(MI) do {                                                              \
        _Pragma("unroll")                                                         \
        for (int ni = 0; ni < 4; ++ni) MFMA8(MI, ni);                             \
    } while (0)

// one K-tile = one barrier: [stage kt+3][lgkm0][16 MFMA, af/bf(kt+1) reloads
// interleaved after last use][vm][barrier]
#define TILE(C0, S, STG_ON, VMC, DONXT, BAR) do {                                 \
        const int nsl = ((C0) + 1) & 3;                                           \
        if (STG_ON) { STG_A8(((C0) + 3) & 3, (S) + 3);                            \
                      STG_B8(((C0) + 3) & 3, (S) + 3); }                          \
        asm volatile("s_waitcnt lgkmcnt(0)" ::: "memory");                        \
        SB;                                                                       \
        __builtin_amdgcn_s_setprio(1);                                            \
        GRP(0); if (DONXT) { RD_A8(0, nsl); } SB;                                 \
        GRP(1); if (DONXT) { RD_A8(1, nsl); } SB;                                 \
        GRP(2); if (DONXT) { RD_A8(2, nsl); } SB;                                 \
        MFMA8(3, 0); if (DONXT) { RD_B8(0, nsl); } SB;                            \
        MFMA8(3, 1); if (DONXT) { RD_B8(1, nsl); } SB;                            \
        MFMA8(3, 2); if (DONXT) { RD_B8(2, nsl); } SB;                            \
        MFMA8(3, 3); if (DONXT) { RD_B8(3, nsl); RD_A8(3, nsl); } SB;             \
        __builtin_amdgcn_s_setprio(0);                                            \
        VMC;                                                                      \
        if (BAR) { __builtin_amdgcn_s_barrier(); SB; }                            \
    } while (0)

    // prologue: stage tiles 0,1,2 (6 loads/wave); VM2 -> tiles 0,1 landed
    STG_A8(0, 0); STG_B8(0, 0);
    STG_A8(1, 1); STG_B8(1, 1);
    STG_A8(2, 2); STG_B8(2, 2);
    VM2;
    __builtin_amdgcn_s_barrier();
    SB;
    RD_A8(0, 0); RD_A8(1, 0); RD_A8(2, 0); RD_A8(3, 0);
    RD_B8(0, 0); RD_B8(1, 0); RD_B8(2, 0); RD_B8(3, 0);

#pragma unroll 1
    for (int it = 0; it < 11; ++it) {         // tiles 0..43, stage kt+3
        const int s0 = it * 4;
        TILE(0, s0 + 0, 1, VM2, 1, 1);
        TILE(1, s0 + 1, 1, VM2, 1, 1);
        TILE(2, s0 + 2, 1, VM2, 1, 1);
        TILE(3, s0 + 3, 1, VM2, 1, 1);
    }
    TILE(0, 44, 1, VM2, 1, 1);                // stages tile 47
    TILE(1, 45, 0, VM0, 1, 1);                // drain: tile 47 landed
    TILE(2, 46, 0, VMX, 1, 1);
    TILE(3, 47, 0, VMX, 0, 0);                // last: no next reads, no barrier

    // epilogue: y = (float)acc * beta * gamma_x[b,o] / 127  (C/D: col=lane&15, row=q*4+r)
    const float beta = *beta_p;
#pragma unroll
    for (int ni = 0; ni < 4; ++ni) {
        const int o = n0 + wn + ni * 16 + lr;
        const float sc = beta * fmaxf(gamma_x[b * C_ + o], 1e-5f) * (1.0f / 127.0f);
#pragma unroll
        for (int mi = 0; mi < 4; ++mi) {
#pragma unroll
            for (int r = 0; r < 4; ++r) {
                const int t = t0 + wm + mi * 16 + q * 4 + r;
                out[(size_t)(b * T_ + t) * C_ + o] = (float)acc[mi][ni][r] * sc;
            }
        }
    }
#undef RD_A8
#undef RD_B8
#undef STG_A8
#undef STG_B8
#undef MFMA8
#undef GRP
#undef TILE
}

// ---------------------------------------------------------------- launch
extern "C" void kernel_launch(void* const* d_in, const int* in_sizes, int n_in,
                              void* d_out, int out_size, void* d_ws, size_t ws_size,
                              hipStream_t stream) {
    const float* x   = (const float*)d_in[0];  // [8,4096,1024] fp32
    const float* lng = (const float*)d_in[1];  // [1024] fp32
    const float* lnb = (const float*)d_in[2];  // [1024] fp32
    const float* W   = (const float*)d_in[3];  // [1024,1024,3] fp32
    float* out = (float*)d_out;                // fp32 output [8,4096,1024]

    char* ws = (char*)d_ws;
    float2*      stats = (float2*)(ws + 0);          //   262144 B
    float*       gamma = (float*) (ws + 262144);     //    32768 B
    double*      wsum  = (double*)(ws + 294912);     //        8 B
    float*       beta  = (float*) (ws + 294920);     //        4 B (+pad)
    signed char* wq8   = (signed char*)(ws + 294928);    // 3145728 B
    signed char* xq8   = (signed char*)(ws + 3440656);   // 33570816 B -> ~37 MB total
    float*       gpart = out;                    // [2048][1024] f32 = 8 MB scratch
    float*       wpart = out + 4 * 1024 * 1024;  // 192 floats @ +16 MB (clear of gpart)

    prefix1_kernel<<<2256,  256, 0, stream>>>(x, lng, lnb, W, stats, gpart, wpart, xq8);
    prefix2_kernel<<<33,    256, 0, stream>>>(gpart, wpart, gamma, wsum);
    quant_kernel  <<<12288, 256, 0, stream>>>(x, stats, lng, lnb, gamma, xq8,
                                              W, wsum, wq8, beta);
    gemm_kernel   <<<dim3(512), 1024, 0, stream>>>(xq8, wq8, gamma, beta, out);
}